// Round 10
// baseline (60.155 us; speedup 1.0000x reference)
//
#include <hip/hip_runtime.h>
#include <math.h>

#define BB 2
#define NN 512
#define IND 64
#define HH 8
#define CC 64          // H*D channels
#define QUADS 16       // channel quads (CC/4)
#define TPB 1024
#define NWAVES 16
#define CH 64          // j-slots per chunk (jg = tid>>4 in 0..63)
#define DEPTH 3        // LDS ring depth

typedef float f4 __attribute__((ext_vector_type(4)));

// async global->LDS, 16B per lane; LDS dest = wave-uniform base + lane*16
__device__ __forceinline__ void gl16(const void* g, void* lds_uniform) {
    __builtin_amdgcn_global_load_lds(
        (const __attribute__((address_space(1))) void*)g,
        (__attribute__((address_space(3))) void*)lds_uniform, 16, 0, 0);
}

// ---------------- Kernel 1: Q,K,V projections ----------------
__global__ __launch_bounds__(64)
void qkv_kernel(const float* __restrict__ h,
                const float* __restrict__ WQ,
                const float* __restrict__ WK,
                const float* __restrict__ WV,
                float* __restrict__ Qw,
                float* __restrict__ Kw,
                float* __restrict__ Vw) {
    int bi = blockIdx.x;
    int c  = threadIdx.x;
    __shared__ float hrow[IND];
    hrow[c] = h[bi * IND + c];
    __syncthreads();
    float aq = 0.f, ak = 0.f, av = 0.f;
#pragma unroll
    for (int k = 0; k < IND; ++k) {
        float hv = hrow[k];
        aq += hv * WQ[c * IND + k];
        ak += hv * WK[c * IND + k];
        av += hv * WV[c * IND + k];
    }
    Qw[bi * CC + c] = aq;
    Kw[bi * CC + c] = ak * 0.35355339059327376f;  // 8^-0.5
    Vw[bi * CC + c] = av;
}

// ---------------- Kernel 2: fused masked softmax-attention ----------------
// One 1024-thread block (16 waves) per (b,i). Thread tid owns (j-slot
// jg=tid>>4, quad q=tid&15). Valid-j compaction as before. The e_att/e_value
// streams are staged via async global_load_lds into a depth-3 LDS ring;
// wave w stages and consumes elements [64w,64w+64) -> per-wave counted
// s_waitcnt vmcnt(5), NO barriers in the hot loop, regalloc cannot
// serialize the pipeline (zero VGPRs per in-flight byte).
__global__ __launch_bounds__(TPB, 4)
void attn_kernel(const float* __restrict__ e_att,
                 const float* __restrict__ e_value,
                 const int*   __restrict__ mask,
                 const float* __restrict__ Qw,
                 const float* __restrict__ Kw,
                 const float* __restrict__ Vw,
                 float* __restrict__ out) {
    int bi   = blockIdx.x;
    int b    = bi >> 9;
    int tid  = threadIdx.x;
    int q    = tid & 15;           // channel quad
    int jg   = tid >> 4;           // j slot 0..63 within a chunk
    int wv   = tid >> 6;           // wave 0..15
    int lane = tid & 63;
    int hh   = q >> 1;             // head of this quad

    __shared__ f4     ea_buf[DEPTH][TPB];     // 48 KB
    __shared__ f4     ev_buf[DEPTH][TPB];     // 48 KB
    __shared__ float  qk_s[NN * HH];          // 16 KB
    __shared__ int    jlist[NN];              // 2 KB
    __shared__ int    wtot[8], woff[8], nvalid_s;
    __shared__ float  Qrow[CC];
    __shared__ float4 wred_l[NWAVES][QUADS];  // 4 KB
    __shared__ float4 wred_a[NWAVES][QUADS];  // 4 KB

    if (tid < CC) Qrow[tid] = Qw[bi * CC + tid];
    if (tid < NN) jlist[tid] = 0;   // pad -> row 0 (weight 0)

    // --- mask compaction (waves 0..7 handle the 512 mask entries) ---
    int valid = 0, rank = 0;
    if (tid < NN) {
        valid = mask[(size_t)bi * NN + tid] != 0;
        unsigned long long ball = __ballot(valid);
        rank = __popcll(ball & ((1ull << lane) - 1ull));
        if (lane == 0) wtot[wv] = __popcll(ball);
    }
    __syncthreads();
    if (tid == 0) {
        int s = 0;
#pragma unroll
        for (int w = 0; w < 8; ++w) { woff[w] = s; s += wtot[w]; }
        nvalid_s = s;
    }
    __syncthreads();
    if (tid < NN && valid) jlist[woff[wv] + rank] = tid;

    const float* Kb = Kw + (size_t)b * NN * CC;

    // qk[j][h] = sum_d Qrow[h*8+d] * Kb[j*64 + h*8 + d]
#pragma unroll
    for (int e = tid; e < NN * HH; e += TPB) {
        int j = e >> 3, h = e & 7;
        const float* kr = Kb + (size_t)j * CC + h * 8;
        float k0[4], k1[4];
        *(float4*)k0 = *(const float4*)(kr);
        *(float4*)k1 = *(const float4*)(kr + 4);
        float s = 0.f;
#pragma unroll
        for (int d = 0; d < 4; ++d) s += Qrow[h * 8 + d] * k0[d];
#pragma unroll
        for (int d = 0; d < 4; ++d) s += Qrow[h * 8 + 4 + d] * k1[d];
        qk_s[e] = s;
    }
    __syncthreads();   // jlist, nvalid_s, qk_s all visible

    const f4* ea_base = (const f4*)(e_att   + (size_t)bi * NN * CC);
    const f4* ev_base = (const f4*)(e_value + (size_t)bi * NN * CC);
    const f4* v_col   = (const f4*)(Vw + (size_t)b * NN * CC) + q;

    int nvalid = nvalid_s;
    int nch = (nvalid + CH - 1) >> 6;
    if (nch < 1) nch = 1;

#define STAGE(t, slot) do {                                                   \
        int _j = jlist[(t) * CH + jg];                                        \
        gl16((const void*)(ea_base + (size_t)_j * QUADS + q),                 \
             (void*)&ea_buf[slot][wv << 6]);                                  \
        gl16((const void*)(ev_base + (size_t)_j * QUADS + q),                 \
             (void*)&ev_buf[slot][wv << 6]);                                  \
    } while (0)

    // prologue: stage chunk0, vv0, chunk1  (outstanding: 2+1+2)
    STAGE(0, 0);
    f4 vvC = v_col[(size_t)jlist[jg] * QUADS];
    asm volatile("" ::: "memory");          // pin vv0 before stage(1)
    if (nch > 1) STAGE(1, 1);

    float l[4] = {0.f, 0.f, 0.f, 0.f};
    float a[4] = {0.f, 0.f, 0.f, 0.f};

    int slot = 0;
    for (int t = 0; t < nch; ++t) {
        // issue next-next stage + next vv (3 new VMEM ops per iter)
        f4 vvN = {0.f, 0.f, 0.f, 0.f};
        if (t + 1 < nch) vvN = v_col[(size_t)jlist[(t + 1) * CH + jg] * QUADS];
        if (t + 2 < nch) {
            int s2 = slot + 2; if (s2 >= DEPTH) s2 -= DEPTH;
            STAGE(t + 2, s2);
            // 8 outstanding -> keep newest 5 (stage t+1, vvN, stage t+2);
            // retires stage(t) + vv_t. Never drains to 0 mid-loop.
            asm volatile("s_waitcnt vmcnt(5)" ::: "memory");
        } else {
            asm volatile("s_waitcnt vmcnt(0)" ::: "memory");   // tail drain
        }
        __builtin_amdgcn_sched_barrier(0);

        int idx  = t * CH + jg;
        int j    = jlist[idx];
        float qk = qk_s[j * HH + hh];
        float w  = (idx < nvalid) ? 1.f : 0.f;
        f4 ea4 = ea_buf[slot][tid];
        f4 ev4 = ev_buf[slot][tid];
#pragma unroll
        for (int cc = 0; cc < 4; ++cc) {
            float s = fminf(qk + ea4[cc], 30.f);   // overflow insurance
            float p = w * __expf(s);
            l[cc] += p;
            a[cc] += p * (vvC[cc] + ev4[cc]);
        }
        vvC = vvN;
        slot = (slot + 1 == DEPTH) ? 0 : slot + 1;
    }
#undef STAGE

    // intra-wave sum over the 4 j-slots in this wave (lanes xor 16, 32)
#pragma unroll
    for (int off = 16; off <= 32; off <<= 1) {
#pragma unroll
        for (int cc = 0; cc < 4; ++cc) {
            l[cc] += __shfl_xor(l[cc], off, 64);
            a[cc] += __shfl_xor(a[cc], off, 64);
        }
    }
    if (lane < QUADS) {
        wred_l[wv][q] = make_float4(l[0], l[1], l[2], l[3]);
        wred_a[wv][q] = make_float4(a[0], a[1], a[2], a[3]);
    }
    __syncthreads();

    // cross-wave sum; threads 0..63 each own one channel
    if (tid < CC) {
        int cq = tid >> 2, sub = tid & 3;
        float L = 0.f, A = 0.f;
#pragma unroll
        for (int w = 0; w < NWAVES; ++w) {
            L += ((const float*)&wred_l[w][cq])[sub];
            A += ((const float*)&wred_a[w][cq])[sub];
        }
        out[(size_t)bi * CC + tid] = (L > 0.f) ? (A / L) : 0.f;
    }
}

extern "C" void kernel_launch(void* const* d_in, const int* in_sizes, int n_in,
                              void* d_out, int out_size, void* d_ws, size_t ws_size,
                              hipStream_t stream) {
    const float* h       = (const float*)d_in[0];
    const float* e_att   = (const float*)d_in[1];
    const float* e_value = (const float*)d_in[2];
    const int*   mask    = (const int*)  d_in[3];
    const float* WQ      = (const float*)d_in[4];
    const float* WK      = (const float*)d_in[5];
    const float* WV      = (const float*)d_in[6];
    float* out = (float*)d_out;

    float* Qw = (float*)d_ws;
    float* Kw = Qw + (size_t)BB * NN * CC;
    float* Vw = Kw + (size_t)BB * NN * CC;

    qkv_kernel<<<BB * NN, 64, 0, stream>>>(h, WQ, WK, WV, Qw, Kw, Vw);
    attn_kernel<<<BB * NN, TPB, 0, stream>>>(e_att, e_value, mask, Qw, Kw, Vw, out);
}

// Round 11
// 49.414 us; speedup vs baseline: 1.2174x; 1.2174x over previous
//
#include <hip/hip_runtime.h>
#include <math.h>

#define BB 2
#define NN 512
#define IND 64
#define HH 8
#define DD 8
#define CC 64          // H*D channels
#define QUADS 16       // channel quads (CC/4)
#define JSLOTS 32      // parallel j slots per block (512 threads / 16 quads)
#define NWAVES 8

typedef float f4 __attribute__((ext_vector_type(4)));

// ---------------- Kernel 1: Q,K,V projections ----------------
__global__ __launch_bounds__(64)
void qkv_kernel(const float* __restrict__ h,
                const float* __restrict__ WQ,
                const float* __restrict__ WK,
                const float* __restrict__ WV,
                float* __restrict__ Qw,
                float* __restrict__ Kw,
                float* __restrict__ Vw) {
    int bi = blockIdx.x;          // b*N + i
    int c  = threadIdx.x;         // 0..63
    __shared__ float hrow[IND];
    hrow[c] = h[bi * IND + c];
    __syncthreads();
    float aq = 0.f, ak = 0.f, av = 0.f;
#pragma unroll
    for (int k = 0; k < IND; ++k) {
        float hv = hrow[k];
        aq += hv * WQ[c * IND + k];
        ak += hv * WK[c * IND + k];
        av += hv * WV[c * IND + k];
    }
    Qw[bi * CC + c] = aq;
    Kw[bi * CC + c] = ak * 0.35355339059327376f;  // 8^-0.5
    Vw[bi * CC + c] = av;
}

// ---------------- Kernel 2: fused masked softmax-attention ----------------
// One block per (b,i), 512 threads = 8 waves, __launch_bounds__(512,4)
// (2 blocks/CU, occ ~52% -- empirically the best point; 71% occ raised
// FETCH_SIZE 30% and regressed, async-LDS staging and register pipelining
// both nulled/regressed -- see rounds 7-10). Valid-j compaction keeps the
// streamed footprint ~214 MB < 256 MB L3 -> warm-replay L3 residency.
__global__ __launch_bounds__(512, 4)
void attn_kernel(const float* __restrict__ e_att,
                 const float* __restrict__ e_value,
                 const int*   __restrict__ mask,
                 const float* __restrict__ Qw,
                 const float* __restrict__ Kw,
                 const float* __restrict__ Vw,
                 float* __restrict__ out) {
    int bi  = blockIdx.x;          // b*N + i
    int b   = bi >> 9;             // / N
    int tid = threadIdx.x;
    int q   = tid & 15;            // channel quad: channels 4q..4q+3
    int jg  = tid >> 4;            // j slot 0..31
    int wv  = tid >> 6;            // wave 0..7
    int hh  = q >> 1;              // head of this quad

    __shared__ float  Qrow[CC];
    __shared__ float  qk_s[NN * HH];          // [j][h], 16 KB
    __shared__ int    jlist[NN];              // compacted valid j, 2 KB
    __shared__ int    wtot[NWAVES], woff[NWAVES];
    __shared__ int    nvalid_s;
    __shared__ float4 wred_l[NWAVES][QUADS];  // per-wave partial l, 2 KB
    __shared__ float4 wred_a[NWAVES][QUADS];  // per-wave partial a, 2 KB

    if (tid < CC) Qrow[tid] = Qw[bi * CC + tid];
    jlist[tid] = 0;                // pad entries point at row 0 (weight 0)

    // --- mask compaction: thread tid owns j = tid ---
    int valid = mask[(size_t)bi * NN + tid] != 0;
    unsigned long long ball = __ballot(valid);
    int lane = tid & 63;
    int rank = __popcll(ball & ((1ull << lane) - 1ull));
    if (lane == 0) wtot[wv] = __popcll(ball);
    __syncthreads();
    if (tid == 0) {
        int s = 0;
#pragma unroll
        for (int w = 0; w < NWAVES; ++w) { woff[w] = s; s += wtot[w]; }
        nvalid_s = s;
    }
    __syncthreads();
    if (valid) jlist[woff[wv] + rank] = tid;

    const float* Kb = Kw + (size_t)b * NN * CC;
    const float* Vb = Vw + (size_t)b * NN * CC;

    // qk[j][h] = sum_d Qrow[h*8+d] * Kb[j*64 + h*8 + d]
#pragma unroll
    for (int e = tid; e < NN * HH; e += 512) {
        int j = e >> 3, h = e & 7;
        const float* kr = Kb + (size_t)j * CC + h * 8;
        float k0[4], k1[4];
        *(float4*)k0 = *(const float4*)(kr);
        *(float4*)k1 = *(const float4*)(kr + 4);
        float s = 0.f;
#pragma unroll
        for (int d = 0; d < 4; ++d) s += Qrow[h * 8 + d] * k0[d];
#pragma unroll
        for (int d = 0; d < 4; ++d) s += Qrow[h * 8 + 4 + d] * k1[d];
        qk_s[e] = s;
    }
    __syncthreads();   // covers jlist, nvalid_s, qk_s

    const f4* ea_row = (const f4*)(e_att   + (size_t)bi * NN * CC) + q;
    const f4* ev_row = (const f4*)(e_value + (size_t)bi * NN * CC) + q;
    const f4* v_col  = (const f4*)Vb + q;

    int nvalid = nvalid_s;
    int nblk   = (nvalid + 127) >> 7;   // each blk = 4 unrolled iters x 32 slots

    float l[4] = {0.f, 0.f, 0.f, 0.f};
    float a[4] = {0.f, 0.f, 0.f, 0.f};

    for (int blk = 0; blk < nblk; ++blk) {
#pragma unroll
        for (int u = 0; u < 4; ++u) {
            int idx = blk * 128 + u * JSLOTS + jg;    // <= 511 always
            int j   = jlist[idx];
            float w = (idx < nvalid) ? 1.f : 0.f;
            f4 ea4 = ea_row[(size_t)j * QUADS];
            f4 ev4 = ev_row[(size_t)j * QUADS];
            f4 vv4 = v_col [(size_t)j * QUADS];
            float qk = qk_s[j * HH + hh];
#pragma unroll
            for (int cc = 0; cc < 4; ++cc) {
                float s = fminf(qk + ea4[cc], 30.f);  // overflow insurance
                float p = w * __expf(s);
                l[cc] += p;
                a[cc] += p * (vv4[cc] + ev4[cc]);
            }
        }
    }

    // intra-wave sum over the 4 j-slots in this wave (lanes xor 16, 32)
#pragma unroll
    for (int off = 16; off <= 32; off <<= 1) {
#pragma unroll
        for (int cc = 0; cc < 4; ++cc) {
            l[cc] += __shfl_xor(l[cc], off, 64);
            a[cc] += __shfl_xor(a[cc], off, 64);
        }
    }
    if ((tid & 63) < QUADS) {
        wred_l[wv][q] = make_float4(l[0], l[1], l[2], l[3]);
        wred_a[wv][q] = make_float4(a[0], a[1], a[2], a[3]);
    }
    __syncthreads();

    // cross-wave sum; threads 0..63 each own one channel
    if (tid < CC) {
        int cq = tid >> 2, sub = tid & 3;
        float L = 0.f, A = 0.f;
#pragma unroll
        for (int w = 0; w < NWAVES; ++w) {
            L += ((const float*)&wred_l[w][cq])[sub];
            A += ((const float*)&wred_a[w][cq])[sub];
        }
        out[(size_t)bi * CC + tid] = (L > 0.f) ? (A / L) : 0.f;
    }
}

extern "C" void kernel_launch(void* const* d_in, const int* in_sizes, int n_in,
                              void* d_out, int out_size, void* d_ws, size_t ws_size,
                              hipStream_t stream) {
    const float* h       = (const float*)d_in[0];
    const float* e_att   = (const float*)d_in[1];
    const float* e_value = (const float*)d_in[2];
    const int*   mask    = (const int*)  d_in[3];
    const float* WQ      = (const float*)d_in[4];
    const float* WK      = (const float*)d_in[5];
    const float* WV      = (const float*)d_in[6];
    float* out = (float*)d_out;

    float* Qw = (float*)d_ws;
    float* Kw = Qw + (size_t)BB * NN * CC;
    float* Vw = Kw + (size_t)BB * NN * CC;

    qkv_kernel<<<BB * NN, 64, 0, stream>>>(h, WQ, WK, WV, Qw, Kw, Vw);
    attn_kernel<<<BB * NN, 512, 0, stream>>>(e_att, e_value, mask, Qw, Kw, Vw, out);
}